// Round 2
// baseline (6271.471 us; speedup 1.0000x reference)
//
#include <hip/hip_runtime.h>
#include <hip/hip_bf16.h>
#include <cstdint>

typedef __hip_bfloat16 bf16;
typedef __attribute__((ext_vector_type(8))) short bfrag;   // 8 bf16 = 4 VGPRs
typedef __attribute__((ext_vector_type(4))) float f32x4;

#define NB 65536   // batch rows

// ---------------------------------------------------------------- helpers
__device__ __forceinline__ void gload16(const void* g, void* l) {
    __builtin_amdgcn_global_load_lds((const __attribute__((address_space(1))) void*)g,
                                     (__attribute__((address_space(3))) void*)l, 16, 0, 0);
}
__device__ __forceinline__ f32x4 mfma16(bfrag a, bfrag b, f32x4 c) {
    return __builtin_amdgcn_mfma_f32_16x16x32_bf16(a, b, c, 0, 0, 0);
}
__device__ __forceinline__ unsigned short f2bfu(float f) {
    bf16 h = __float2bfloat16(f);
    return *reinterpret_cast<unsigned short*>(&h);
}
__device__ __forceinline__ bf16 bfu2bf(unsigned short u) {
    bf16 h; *reinterpret_cast<unsigned short*>(&h) = u; return h;
}
__device__ __forceinline__ float bfu2f(unsigned short u) {
    return __uint_as_float(((unsigned)u) << 16);
}
__device__ __forceinline__ float sigmoidf_(float x) { return 1.0f / (1.0f + __expf(-x)); }

// ---------------------------------------------------------------- prep kernels
__global__ void cast_slice(const float* __restrict__ src, bf16* __restrict__ dst,
                           int rows, int src_cols, int col0, int ncols)
{
    long n = (long)rows * ncols;
    for (long i = blockIdx.x * 256L + threadIdx.x; i < n; i += (long)gridDim.x * 256L) {
        long r = i / ncols; int c = (int)(i - r * ncols);
        dst[i] = __float2bfloat16(src[r * src_cols + col0 + c]);
    }
}

// dst [4 groups][6 pieces][64][256]; pieces 0..2 from ih (cols col0:col0+256), 3..5 from hh
__global__ void perm6(const float* __restrict__ ih, int ih_cols, int col0,
                      const float* __restrict__ hh, bf16* __restrict__ dst)
{
    const long n = 1536L * 256;
    for (long i = blockIdx.x * 256L + threadIdx.x; i < n; i += (long)gridDim.x * 256L) {
        int d = (int)(i >> 8); int c = (int)(i & 255);
        int g = d / 384; int rem = d - g * 384; int p = rem / 64; int r = rem & 63;
        int srow = (p % 3) * 256 + g * 64 + r;
        float v = (p < 3) ? ih[(long)srow * ih_cols + col0 + c]
                          : hh[(long)srow * 256 + c];
        dst[i] = __float2bfloat16(v);
    }
}

// dst [4 groups][3 pieces][64][256] from src rows (p*256 + g*64 + r), cols col0..col0+255
__global__ void perm3(const float* __restrict__ src, int src_cols, int col0,
                      bf16* __restrict__ dst)
{
    const long n = 768L * 256;
    for (long i = blockIdx.x * 256L + threadIdx.x; i < n; i += (long)gridDim.x * 256L) {
        int d = (int)(i >> 8); int c = (int)(i & 255);
        int g = d / 192; int rem = d - g * 192; int p = rem / 64; int r = rem & 63;
        int srow = p * 256 + g * 64 + r;
        dst[i] = __float2bfloat16(src[(long)srow * src_cols + col0 + c]);
    }
}

// ---------------------------------------------------------------- generic GEMM (prep only)
__global__ __launch_bounds__(256, 2)
void gemm_kernel(const bf16* __restrict__ A, int K,
                 const bf16* __restrict__ W, const float* __restrict__ bias,
                 bf16* __restrict__ Cout, int N, int act)
{
    __shared__ bf16 lA[128 * 32];
    __shared__ bf16 lB[128 * 32];
    const int t = threadIdx.x;
    const int l = t & 63;
    const int w = t >> 6;
    const int wr = w >> 1, wc = w & 1;
    const long m0 = (long)blockIdx.y * 128;
    const int n0 = blockIdx.x * 128;
    const int srow = t >> 2;
    const int scol = (t & 3) * 8;

    f32x4 acc[4][4] = {};
    const int nsteps = K >> 5;
    for (int s = 0; s < nsteps; ++s) {
        const int k0 = s * 32;
        gload16(A + (m0 + srow) * K + k0 + scol,        (char*)lA + t * 16);
        gload16(A + (m0 + 64 + srow) * K + k0 + scol,   (char*)lA + 4096 + t * 16);
        gload16(W + (long)(n0 + srow) * K + k0 + scol,      (char*)lB + t * 16);
        gload16(W + (long)(n0 + 64 + srow) * K + k0 + scol, (char*)lB + 4096 + t * 16);
        __syncthreads();
        bfrag af[4], bfr[4];
        #pragma unroll
        for (int m = 0; m < 4; ++m)
            af[m] = *(const bfrag*)(lA + (wr * 64 + m * 16 + (l & 15)) * 32 + 8 * (l >> 4));
        #pragma unroll
        for (int n = 0; n < 4; ++n)
            bfr[n] = *(const bfrag*)(lB + (wc * 64 + n * 16 + (l & 15)) * 32 + 8 * (l >> 4));
        #pragma unroll
        for (int m = 0; m < 4; ++m)
            #pragma unroll
            for (int n = 0; n < 4; ++n)
                acc[m][n] = mfma16(af[m], bfr[n], acc[m][n]);
        __syncthreads();
    }

    const int colb = n0 + wc * 64 + (l & 15);
    const int rloc = wr * 64 + 4 * (l >> 4);
    #pragma unroll
    for (int m = 0; m < 4; ++m) {
        #pragma unroll
        for (int n = 0; n < 4; ++n) {
            const int c = colb + n * 16;
            const float bb = bias ? bias[c] : 0.0f;
            #pragma unroll
            for (int q = 0; q < 4; ++q) {
                const long r = m0 + rloc + m * 16 + q;
                float v = acc[m][n][q] + bb;
                if (act == 1) v = 0.5f * v * (1.0f + erff(v * 0.70710678f));
                Cout[r * N + c] = __float2bfloat16(v);
            }
        }
    }
}

// ---------------------------------------------------------------- mega kernel pieces
// weight stage: dst [P][64 rows][32 k] bf16, chunk(16B)-swizzled: dst chunk c holds
// source chunk c ^ ((row>>1)&3)  (involution; read applies same XOR)
template<int P>
__device__ __forceinline__ void stage_w(const bf16* __restrict__ Wg, int k0,
                                        bf16* dst, int t)
{
    #pragma unroll
    for (int i = t; i < P * 256; i += 512) {
        const int p = i >> 8, row = (i >> 2) & 63, c = i & 3;
        gload16(Wg + ((p * 64 + row) << 8) + k0 + ((c ^ ((row >> 1) & 3)) << 3),
                (char*)dst + i * 16);
    }
}

// z-state LDS element address for logical (row r, unit u): chunk-XOR swizzle
__device__ __forceinline__ int zaddr(int r, int u) {
    return r * 256 + (((u >> 3) ^ (r & 7)) << 3) + (u & 7);
}

// One GEMM pass: acc[p][m] += A[64x256] @ Wg[p*64+u][256]^T, 2-phase staged weights.
template<int P>
__device__ __forceinline__ void gemm_pass(const bf16* __restrict__ Wg,
                                          const bf16* lA, bf16 (*wst)[6 * 64 * 32],
                                          f32x4 (*acc)[2],
                                          int t, int rh, int ws, int lr, int lh)
{
    stage_w<P>(Wg, 0, wst[0], t);
    __syncthreads();
    const int ar0 = rh * 32 + lr;
    const int urow = ws * 16 + lr;
    const int bsw = (lh ^ ((urow >> 1) & 3)) << 3;
    for (int kk = 0; kk < 8; ++kk) {
        const bf16* cb = wst[kk & 1];
        if (kk < 7) stage_w<P>(Wg, (kk + 1) * 32, wst[(kk + 1) & 1], t);
        const int ch = kk * 4 + lh;
        bfrag af0 = *(const bfrag*)(lA + ar0 * 256        + ((ch ^ (ar0 & 7)) << 3));
        bfrag af1 = *(const bfrag*)(lA + (ar0 + 16) * 256 + ((ch ^ (ar0 & 7)) << 3));
        #pragma unroll
        for (int p = 0; p < P; ++p) {
            bfrag bw = *(const bfrag*)(cb + ((p * 64 + urow) << 5) + bsw);
            acc[p][0] = mfma16(af0, bw, acc[p][0]);
            acc[p][1] = mfma16(af1, bw, acc[p][1]);
        }
        __syncthreads();
    }
}

// ---------------------------------------------------------------- the mega kernel
// One block = 64 batch rows, runs the ENTIRE recurrence for its rows.
__global__ __launch_bounds__(512, 2)
void mega_kernel(const bf16* __restrict__ Gx,
                 const bf16* __restrict__ WlowP, const bf16* __restrict__ WhP,
                 const bf16* __restrict__ VlP,   const bf16* __restrict__ WhighP,
                 const float* __restrict__ low_b_hh,
                 const float* __restrict__ high_b_ih, const float* __restrict__ high_b_hh,
                 float* __restrict__ out_zh, float* __restrict__ out_zl)
{
    __shared__ bf16 zl[64 * 256];
    __shared__ bf16 zh[64 * 256];
    __shared__ bf16 wst[2][6 * 64 * 32];

    const int t  = threadIdx.x;
    const int l  = t & 63;
    const int w  = t >> 6;
    const int rh = w >> 2;      // row half 0/1
    const int ws = w & 3;       // 16-unit strip within 64-unit group
    const int lr = l & 15;
    const int lh = l >> 4;
    const long m0 = (long)blockIdx.x * 64;

    for (int i = t; i < 64 * 256; i += 512) {
        zl[i] = __float2bfloat16(0.0f);
        zh[i] = __float2bfloat16(0.0f);
    }

    // preload low-cell b_hh per group
    float blr[4], blz[4], bln[4];
    #pragma unroll
    for (int g = 0; g < 4; ++g) {
        const int u = g * 64 + ws * 16 + lr;
        blr[g] = low_b_hh[u]; blz[g] = low_b_hh[256 + u]; bln[g] = low_b_hh[512 + u];
    }
    __syncthreads();

    for (int cyc = 0; cyc < 3; ++cyc) {
        // ---- build Gxh = Gx (+ z_h @ Wh^T for cyc>0), packed bf16 in registers
        unsigned gxh_pk[4][3][2][2];
        #pragma unroll
        for (int g = 0; g < 4; ++g) {
            f32x4 a3[3][2] = {};
            if (cyc > 0)
                gemm_pass<3>(WhP + (size_t)g * 3 * 64 * 256, zh, wst, a3, t, rh, ws, lr, lh);
            const int u = g * 64 + ws * 16 + lr;
            #pragma unroll
            for (int p = 0; p < 3; ++p)
                #pragma unroll
                for (int m = 0; m < 2; ++m)
                    #pragma unroll
                    for (int qq = 0; qq < 2; ++qq) {
                        const int r0 = rh * 32 + m * 16 + lh * 4 + qq * 2;
                        float v0 = __bfloat162float(Gx[(m0 + r0)     * 768 + p * 256 + u]) + a3[p][m][qq * 2];
                        float v1 = __bfloat162float(Gx[(m0 + r0 + 1) * 768 + p * 256 + u]) + a3[p][m][qq * 2 + 1];
                        gxh_pk[g][p][m][qq] = (unsigned)f2bfu(v0) | (((unsigned)f2bfu(v1)) << 16);
                    }
        }

        // ---- 4 low GRU steps
        for (int s = 0; s < 4; ++s) {
            const bool last_low = (cyc == 2 && s == 3);
            unsigned zst[4][2][2];
            #pragma unroll
            for (int g = 0; g < 4; ++g) {
                f32x4 acc[6][2] = {};
                gemm_pass<6>(WlowP + (size_t)g * 6 * 64 * 256, zl, wst, acc, t, rh, ws, lr, lh);
                const int u = g * 64 + ws * 16 + lr;
                #pragma unroll
                for (int m = 0; m < 2; ++m)
                    #pragma unroll
                    for (int q = 0; q < 4; ++q) {
                        const int rr_ = rh * 32 + m * 16 + lh * 4 + q;
                        const unsigned pk = gxh_pk[g][0][m][q >> 1];
                        const unsigned pz = gxh_pk[g][1][m][q >> 1];
                        const unsigned pn = gxh_pk[g][2][m][q >> 1];
                        const float gxr = bfu2f((unsigned short)((q & 1) ? (pk >> 16) : (pk & 0xffff)));
                        const float gxz = bfu2f((unsigned short)((q & 1) ? (pz >> 16) : (pz & 0xffff)));
                        const float gxn = bfu2f((unsigned short)((q & 1) ? (pn >> 16) : (pn & 0xffff)));
                        const float gr = gxr + acc[0][m][q] + acc[3][m][q] + blr[g];
                        const float gz = gxz + acc[1][m][q] + acc[4][m][q] + blz[g];
                        const float gn = gxn + acc[2][m][q];
                        const float hn = acc[5][m][q] + bln[g];
                        const float r_ = sigmoidf_(gr);
                        const float z_ = sigmoidf_(gz);
                        const float n_ = tanhf(gn + r_ * hn);
                        const float h_ = __bfloat162float(zl[zaddr(rr_, u)]);
                        const float ho = (1.0f - z_) * n_ + z_ * h_;
                        if (q & 1) zst[g][m][q >> 1] |= ((unsigned)f2bfu(ho)) << 16;
                        else       zst[g][m][q >> 1]  = (unsigned)f2bfu(ho);
                        if (last_low) out_zl[(m0 + rr_) * 256 + u] = ho;
                    }
            }
            __syncthreads();
            #pragma unroll
            for (int g = 0; g < 4; ++g) {
                const int u = g * 64 + ws * 16 + lr;
                #pragma unroll
                for (int m = 0; m < 2; ++m)
                    #pragma unroll
                    for (int qq = 0; qq < 2; ++qq) {
                        const int r0 = rh * 32 + m * 16 + lh * 4 + qq * 2;
                        zl[zaddr(r0, u)]     = bfu2bf((unsigned short)(zst[g][m][qq] & 0xffff));
                        zl[zaddr(r0 + 1, u)] = bfu2bf((unsigned short)(zst[g][m][qq] >> 16));
                    }
            }
            __syncthreads();
        }

        // ---- high GRU step
        {
            unsigned hst[4][2][2];
            #pragma unroll
            for (int g = 0; g < 4; ++g) {
                f32x4 acc[6][2] = {};
                gemm_pass<3>(VlP + (size_t)g * 3 * 64 * 256, zl, wst, acc, t, rh, ws, lr, lh);
                if (cyc > 0)
                    gemm_pass<6>(WhighP + (size_t)g * 6 * 64 * 256, zh, wst, acc, t, rh, ws, lr, lh);
                const int u = g * 64 + ws * 16 + lr;
                const float bir = high_b_ih[u],      bhr = high_b_hh[u];
                const float biz = high_b_ih[256 + u], bhz = high_b_hh[256 + u];
                const float bin_ = high_b_ih[512 + u], bhn = high_b_hh[512 + u];
                #pragma unroll
                for (int m = 0; m < 2; ++m)
                    #pragma unroll
                    for (int q = 0; q < 4; ++q) {
                        const int rr_ = rh * 32 + m * 16 + lh * 4 + q;
                        const float r_ = sigmoidf_(acc[0][m][q] + bir + acc[3][m][q] + bhr);
                        const float z_ = sigmoidf_(acc[1][m][q] + biz + acc[4][m][q] + bhz);
                        const float n_ = tanhf(acc[2][m][q] + bin_ + r_ * (acc[5][m][q] + bhn));
                        const float h_ = __bfloat162float(zh[zaddr(rr_, u)]);
                        const float ho = (1.0f - z_) * n_ + z_ * h_;
                        if (q & 1) hst[g][m][q >> 1] |= ((unsigned)f2bfu(ho)) << 16;
                        else       hst[g][m][q >> 1]  = (unsigned)f2bfu(ho);
                        if (cyc == 2) out_zh[(m0 + rr_) * 256 + u] = ho;
                    }
            }
            __syncthreads();
            #pragma unroll
            for (int g = 0; g < 4; ++g) {
                const int u = g * 64 + ws * 16 + lr;
                #pragma unroll
                for (int m = 0; m < 2; ++m)
                    #pragma unroll
                    for (int qq = 0; qq < 2; ++qq) {
                        const int r0 = rh * 32 + m * 16 + lh * 4 + qq * 2;
                        zh[zaddr(r0, u)]     = bfu2bf((unsigned short)(hst[g][m][qq] & 0xffff));
                        zh[zaddr(r0 + 1, u)] = bfu2bf((unsigned short)(hst[g][m][qq] >> 16));
                    }
            }
            __syncthreads();
        }
    }
}

// ---------------------------------------------------------------- output head
__global__ __launch_bounds__(256)
void head_kernel(const float* __restrict__ zh, const float* __restrict__ g,
                 const float* __restrict__ b, const float* __restrict__ ow,
                 const float* __restrict__ ob, float* __restrict__ out)
{
    const int t = threadIdx.x, l = t & 63, sub = t >> 6;
    const long row = blockIdx.x * 4L + sub;
    const float* zr = zh + row * 256;
    const float4 v = *(const float4*)(zr + l * 4);
    float s  = v.x + v.y + v.z + v.w;
    float sq = v.x * v.x + v.y * v.y + v.z * v.z + v.w * v.w;
    #pragma unroll
    for (int o = 32; o >= 1; o >>= 1) { s += __shfl_xor(s, o, 64); sq += __shfl_xor(sq, o, 64); }
    const float mu = s * (1.0f / 256.0f);
    const float var = sq * (1.0f / 256.0f) - mu * mu;
    const float rs = rsqrtf(var + 1e-5f);
    const float4 gg = *(const float4*)(g + l * 4);
    const float4 bb = *(const float4*)(b + l * 4);
    const float n0 = (v.x - mu) * rs * gg.x + bb.x;
    const float n1 = (v.y - mu) * rs * gg.y + bb.y;
    const float n2 = (v.z - mu) * rs * gg.z + bb.z;
    const float n3 = (v.w - mu) * rs * gg.w + bb.w;
    const float4 w0 = *(const float4*)(ow + l * 4);
    const float4 w1 = *(const float4*)(ow + 256 + l * 4);
    float p0 = n0 * w0.x + n1 * w0.y + n2 * w0.z + n3 * w0.w;
    float p1 = n0 * w1.x + n1 * w1.y + n2 * w1.z + n3 * w1.w;
    #pragma unroll
    for (int o = 32; o >= 1; o >>= 1) { p0 += __shfl_xor(p0, o, 64); p1 += __shfl_xor(p1, o, 64); }
    if (l == 0) { out[row * 2] = p0 + ob[0]; out[row * 2 + 1] = p1 + ob[1]; }
}

// ---------------------------------------------------------------- launch
extern "C" void kernel_launch(void* const* d_in, const int* in_sizes, int n_in,
                              void* d_out, int out_size, void* d_ws, size_t ws_size,
                              hipStream_t stream)
{
    (void)in_sizes; (void)n_in; (void)out_size; (void)ws_size;
    const float* x         = (const float*)d_in[0];
    const float* proj_w    = (const float*)d_in[1];
    const float* proj_b    = (const float*)d_in[2];
    const float* low_w_ih  = (const float*)d_in[3];
    const float* low_w_hh  = (const float*)d_in[4];
    const float* low_b_ih  = (const float*)d_in[5];
    const float* low_b_hh  = (const float*)d_in[6];
    const float* high_w_ih = (const float*)d_in[7];
    const float* high_w_hh = (const float*)d_in[8];
    const float* high_b_ih = (const float*)d_in[9];
    const float* high_b_hh = (const float*)d_in[10];
    const float* ln_g      = (const float*)d_in[11];
    const float* ln_b      = (const float*)d_in[12];
    const float* out_w     = (const float*)d_in[13];
    const float* out_b     = (const float*)d_in[14];

    char* ws = (char*)d_ws;
    size_t off = 0;
    auto alloc = [&](size_t bytes) -> void* {
        void* p = ws + off; off += (bytes + 255) & ~(size_t)255; return p;
    };
    bf16* WlowP  = (bf16*)alloc(1536 * 256 * 2);
    bf16* WhighP = (bf16*)alloc(1536 * 256 * 2);
    bf16* VlP    = (bf16*)alloc(768 * 256 * 2);
    bf16* WhP    = (bf16*)alloc(768 * 256 * 2);
    bf16* Wx     = (bf16*)alloc(768 * 256 * 2);
    bf16* Pw     = (bf16*)alloc(256 * 512 * 2);
    bf16* R1     = (bf16*)alloc((size_t)NB * 768 * 2);   // x_bf16, then Gx
    bf16* Xemb   = (bf16*)alloc((size_t)NB * 256 * 2);
    bf16* xbf = R1;
    bf16* Gx  = R1;

    float* out_zh = (float*)d_out;
    float* out_zl = out_zh + (size_t)NB * 256;
    float* out_lg = out_zl + (size_t)NB * 256;

    // weight prep + x cast
    cast_slice<<<256, 256, 0, stream>>>(proj_w, Pw, 256, 512, 0, 512);
    cast_slice<<<256, 256, 0, stream>>>(low_w_ih, Wx, 768, 768, 0, 256);
    perm6<<<256, 256, 0, stream>>>(low_w_ih, 768, 512, low_w_hh, WlowP);
    perm6<<<256, 256, 0, stream>>>(high_w_ih, 512, 256, high_w_hh, WhighP);
    perm3<<<256, 256, 0, stream>>>(high_w_ih, 512, 0, VlP);
    perm3<<<256, 256, 0, stream>>>(low_w_ih, 768, 256, WhP);
    cast_slice<<<2048, 256, 0, stream>>>(x, xbf, NB, 512, 0, 512);

    // x_embed = gelu(x @ proj_w.T + proj_b)
    gemm_kernel<<<dim3(2, NB / 128), 256, 0, stream>>>(xbf, 512, Pw, proj_b, Xemb, 256, 1);
    // Gx = x_embed @ Wx.T + low_b_ih   (overwrites xbf region; xbf is dead)
    gemm_kernel<<<dim3(6, NB / 128), 256, 0, stream>>>(Xemb, 256, Wx, low_b_ih, Gx, 768, 0);

    // the entire recurrence in one kernel
    mega_kernel<<<NB / 64, 512, 0, stream>>>(Gx, WlowP, WhP, VlP, WhighP,
                                             low_b_hh, high_b_ih, high_b_hh,
                                             out_zh, out_zl);

    head_kernel<<<NB / 4, 256, 0, stream>>>(out_zh, ln_g, ln_b, out_w, out_b, out_lg);
}